// Round 17
// baseline (241.789 us; speedup 1.0000x reference)
//
#include <hip/hip_runtime.h>
#include <hip/hip_bf16.h>

// FractalTransformer fused kernels, round 17.
// vs r16 (118.1us; attn 98.2): two residual cuts. (1) v fragments stored
// f32 (vfrag 1MB, L2-resident) -> update loses 8 v_cvt_f32_f16 per tile
// per lane (~17% of update VALU); written directly by the fused qkv
// epilogue. (2) prep_weights merged with the first linear into one
// dispatch (blocks 0..191 convert the 6 remaining weights; blocks 192..447
// compute X = x@w_pre^T reading w_pre f32 + inline cvt) -> one fewer
// launch gap. Attn schedule = r11 verbatim otherwise.

typedef __attribute__((ext_vector_type(8))) short short8;
typedef __attribute__((ext_vector_type(4))) float f32x4;
typedef __attribute__((ext_vector_type(8))) _Float16 half8;
typedef __attribute__((ext_vector_type(4))) _Float16 half4;

#define DD 256
#define SS 512
#define LOG2E 1.4426950408889634f
#define LN2   0.6931471805599453f

__device__ __forceinline__ unsigned short f2bf(float f) {
  unsigned int b = __float_as_uint(f);
  b += 0x7FFFu + ((b >> 16) & 1u);   // RNE
  return (unsigned short)(b >> 16);
}
__device__ __forceinline__ short8 cvt8(f32x4 lo, f32x4 hi) {
  short8 r;
  r[0]=(short)f2bf(lo[0]); r[1]=(short)f2bf(lo[1]);
  r[2]=(short)f2bf(lo[2]); r[3]=(short)f2bf(lo[3]);
  r[4]=(short)f2bf(hi[0]); r[5]=(short)f2bf(hi[1]);
  r[6]=(short)f2bf(hi[2]); r[7]=(short)f2bf(hi[3]);
  return r;
}
__device__ __forceinline__ void gload16(const void* g, void* l) {
  __builtin_amdgcn_global_load_lds(
      (const __attribute__((address_space(1))) void*)g,
      (__attribute__((address_space(3))) void*)l,
      16, 0, 0);
}

// ------------------------------------------------------------------
// Fused: blocks 0..191 = bf16/f16-convert the 6 weights still needed
// after this dispatch (q,k,va,vo,end -> bf16; wal+I -> f16);
// blocks 192..447 = X = x @ w_pre^T (w_pre read f32, inline cvt).
// ------------------------------------------------------------------
__global__ __launch_bounds__(256) void prep_and_X(
    const float* __restrict__ x,  const float* __restrict__ w_pre,
    const float* __restrict__ w1, const float* __restrict__ w2,
    const float* __restrict__ w3, const float* __restrict__ w4,
    const float* __restrict__ w5, const float* __restrict__ wal,
    unsigned short* __restrict__ wbf, float* __restrict__ X)
{
  const int bi = blockIdx.x;
  const int tid = threadIdx.x;
  if (bi < 192) {
    const int m = 1 + (bi >> 5);           // wbf slots 1..6
    const int off = ((bi & 31) * 256 + tid) * 8;
    const float* src = m==1?w1: m==2?w2: m==3?w3: m==4?w4: m==5?w5: wal;
    f32x4 a = *(const f32x4*)(src + off);
    f32x4 b = *(const f32x4*)(src + off + 4);
    if (m == 6) {                          // wal: fold +I, store f16
      const int e = off >> 8, d = off & 255;
#pragma unroll
      for (int jj = 0; jj < 4; ++jj) {
        if (e == d + jj)     a[jj] += 1.0f;
        if (e == d + 4 + jj) b[jj] += 1.0f;
      }
      half8 h;
#pragma unroll
      for (int jj = 0; jj < 4; ++jj) {
        h[jj]     = (_Float16)a[jj];
        h[jj + 4] = (_Float16)b[jj];
      }
      *(half8*)(wbf + (size_t)m * 65536 + off) = h;
    } else {
      *(short8*)(wbf + (size_t)m * 65536 + off) = cvt8(a, b);
    }
    return;
  }

  // ---- X = x @ w_pre^T ----
  const int bi2 = bi - 192;
  const int rb = (bi2 >> 2) * 16;
  const int cb = (bi2 & 3) * 64;
  const int wv = tid >> 6, lane = tid & 63;
  const int g = lane >> 4, c = lane & 15;
  const int arow = rb + c;
  const int wrow = cb + wv * 16 + c;

  f32x4 acc = (f32x4){0.f, 0.f, 0.f, 0.f};
#pragma unroll
  for (int ks = 0; ks < 8; ++ks) {
    const int d0 = ks * 32 + g * 8;
    f32x4 a0 = *(const f32x4*)(x + arow * DD + d0);
    f32x4 a1 = *(const f32x4*)(x + arow * DD + d0 + 4);
    short8 av = cvt8(a0, a1);
    f32x4 b0 = *(const f32x4*)(w_pre + wrow * DD + d0);
    f32x4 b1 = *(const f32x4*)(w_pre + wrow * DD + d0 + 4);
    short8 bv = cvt8(b0, b1);
    acc = __builtin_amdgcn_mfma_f32_16x16x32_bf16(av, bv, acc, 0, 0, 0);
  }
#pragma unroll
  for (int j = 0; j < 4; ++j)
    X[(rb + g * 4 + j) * DD + cb + wv * 16 + c] = acc[j];
}

// ------------------------------------------------------------------
// out[1024,256] = A @ Wbf^T (+res1)(+res2). grid 256 = 64 rowblk x 4 colblk.
// ------------------------------------------------------------------
__global__ __launch_bounds__(256) void linear_bf(
    const float* __restrict__ A, const unsigned short* __restrict__ Wbf,
    const float* __restrict__ res1, const float* __restrict__ res2,
    float* __restrict__ out)
{
  const int bi = blockIdx.x;
  const int rb = (bi >> 2) * 16;
  const int cb = (bi & 3) * 64;
  const int tid = threadIdx.x;
  const int wv = tid >> 6, lane = tid & 63;
  const int g = lane >> 4, c = lane & 15;
  const int arow = rb + c;
  const int wrow = cb + wv * 16 + c;

  f32x4 acc = (f32x4){0.f, 0.f, 0.f, 0.f};
#pragma unroll
  for (int ks = 0; ks < 8; ++ks) {
    const int d0 = ks * 32 + g * 8;
    f32x4 a0 = *(const f32x4*)(A + arow * DD + d0);
    f32x4 a1 = *(const f32x4*)(A + arow * DD + d0 + 4);
    short8 av = cvt8(a0, a1);
    short8 bv = *(const short8*)(Wbf + wrow * DD + d0);
    acc = __builtin_amdgcn_mfma_f32_16x16x32_bf16(av, bv, acc, 0, 0, 0);
  }
#pragma unroll
  for (int j = 0; j < 4; ++j) {
    const int ro = rb + g * 4 + j;
    const int co = cb + wv * 16 + c;
    float v = acc[j];
    if (res1) v += res1[ro * DD + co];
    if (res2) v += res2[ro * DD + co];
    out[ro * DD + co] = v;
  }
}

// ------------------------------------------------------------------
// q = f16((X + X@Wq^T)*log2e);  k = f16(...) fragment-packed;
// v = f32(...) fragment-packed. (pack fused via LDS transpose.)
// ------------------------------------------------------------------
__global__ __launch_bounds__(256) void linear_qkv(
    const float* __restrict__ X,
    const unsigned short* __restrict__ Wq, const unsigned short* __restrict__ Wk,
    const unsigned short* __restrict__ Wv,
    _Float16* __restrict__ qout,
    _Float16* __restrict__ kfrag, float* __restrict__ vfrag)
{
  __shared__ _Float16 kl[16][64];
  __shared__ float    vl[16][64];

  const int bi = blockIdx.x;
  const int rb = (bi >> 2) * 16;
  const int cb = (bi & 3) * 64;
  const int tid = threadIdx.x;
  const int wv = tid >> 6, lane = tid & 63;
  const int g = lane >> 4, c = lane & 15;
  const int arow = rb + c;
  const int wrow = cb + wv * 16 + c;

  f32x4 aq = (f32x4){0.f,0.f,0.f,0.f};
  f32x4 ak = (f32x4){0.f,0.f,0.f,0.f};
  f32x4 av_ = (f32x4){0.f,0.f,0.f,0.f};
#pragma unroll
  for (int ks = 0; ks < 8; ++ks) {
    const int d0 = ks * 32 + g * 8;
    f32x4 a0 = *(const f32x4*)(X + arow * DD + d0);
    f32x4 a1 = *(const f32x4*)(X + arow * DD + d0 + 4);
    short8 af = cvt8(a0, a1);
    short8 bq = *(const short8*)(Wq + wrow * DD + d0);
    aq = __builtin_amdgcn_mfma_f32_16x16x32_bf16(af, bq, aq, 0, 0, 0);
    short8 bk = *(const short8*)(Wk + wrow * DD + d0);
    ak = __builtin_amdgcn_mfma_f32_16x16x32_bf16(af, bk, ak, 0, 0, 0);
    short8 bv = *(const short8*)(Wv + wrow * DD + d0);
    av_ = __builtin_amdgcn_mfma_f32_16x16x32_bf16(af, bv, av_, 0, 0, 0);
  }
#pragma unroll
  for (int j = 0; j < 4; ++j) {
    const int ro = rb + g * 4 + j;
    const int co = cb + wv * 16 + c;
    const float base = X[ro * DD + co];
    qout[ro * DD + co] = (_Float16)((base + aq[j]) * LOG2E);
    kl[g * 4 + j][wv * 16 + c] = (_Float16)(base + ak[j]);
    vl[g * 4 + j][wv * 16 + c] = base + av_[j];
  }
  __syncthreads();

  const int b  = rb >> 9;
  const int t2 = (rb >> 4) & 31;
  const int cg = cb >> 5;                  // ks / slice base (0,2,4,6)

  // k fragment chunks: threads 0..127 -> 2 chunks x 64 lanes x 8 f16
  if (tid < 128) {
    const int ksl = tid >> 6, lane2 = tid & 63;
    const int g2 = lane2 >> 4, c2 = lane2 & 15;
    half8 h = *(const half8*)&kl[c2][ksl * 32 + g2 * 8];
    *(half8*)(kfrag + (size_t)b * 131072 + (size_t)t2 * 4096
              + (cg + ksl) * 512 + lane2 * 8) = h;
  }
  // v fragment chunks (f32): 2 slices x 2 i x 64 lanes x 4 f32
  {
    const int sl = tid >> 7, il = (tid >> 6) & 1, lane2 = tid & 63;
    const int g2 = lane2 >> 4, c2 = lane2 & 15;
    f32x4 h = *(const f32x4*)&vl[c2][sl * 32 + il * 16 + g2 * 4];
    *(f32x4*)(vfrag + (size_t)b * 131072 + (size_t)t2 * 4096
              + (cg + sl) * 512 + il * 256 + lane2 * 4) = h;
  }
}

// ------------------------------------------------------------------
// Fused fractal attention — r11 schedule; v now f32 (no unpack in update).
// Grid 2048 = b x sq x eh; 4 waves. slice = eh*4+wv owns e [slice*32,+32).
// ------------------------------------------------------------------
__global__ __launch_bounds__(256, 3) void fractal_attn(
    const _Float16* __restrict__ walI,   // f16 (wal+I), [256][256]
    const _Float16* __restrict__ qf,     // f16, pre-scaled by log2e
    const _Float16* __restrict__ kfrag,  // f16 fragment-packed
    const float* __restrict__ vfrag,     // f32 fragment-packed (slice-32)
    float* __restrict__ vsum)
{
  __shared__ _Float16 kt[2][4096];       // 2 x 8KB k tiles

  const int bid = blockIdx.x;            // 2048
  const int eh = bid & 1;
  const int sq = (bid >> 1) & 511;
  const int b  = bid >> 10;
  const int tid = threadIdx.x;
  const int wv = tid >> 6;
  const int lane = tid & 63;
  const int g = lane >> 4, c = lane & 15;
  const int slice = eh * 4 + wv;
  const int sbase = slice * 32;

  const _Float16* ktile0 = kfrag + (size_t)b * 131072;
  auto stage = [&](int t) {
    const _Float16* src = ktile0 + (size_t)t * 4096;
    _Float16* dst = &kt[t & 1][0];
    gload16(src + tid * 8,        dst + tid * 8);
    gload16(src + 2048 + tid * 8, dst + 2048 + tid * 8);
  };

  stage(0);   // completes while we build A'

  half8 afrag[2][8];
  {
    const _Float16* qrow = qf + (size_t)(b * SS + sq) * DD;
    half8 q8[8];
#pragma unroll
    for (int ks = 0; ks < 8; ++ks)
      q8[ks] = *(const half8*)(qrow + ks * 32 + g * 8);
#pragma unroll
    for (int i = 0; i < 2; ++i) {
      const int e = sbase + i * 16 + c;
      const _Float16* wrow = walI + (size_t)e * DD;
#pragma unroll
      for (int ks = 0; ks < 8; ++ks)
        afrag[i][ks] = (*(const half8*)(wrow + ks * 32 + g * 8)) * q8[ks];
    }
  }

  const float* vfb = vfrag + (size_t)b * 131072 + slice * 512 + lane * 4;

  float mst[8], sst[8], vst[8];
#pragma unroll
  for (int s = 0; s < 8; ++s) { mst[s] = -1e30f; sst[s] = 0.f; vst[s] = 0.f; }

  half8 bf[8];
  f32x4 vqA[2], vqB[2];
  f32x4 accA[2], accB[2];
  const f32x4 zeroc = (f32x4){0.f, 0.f, 0.f, 0.f};

#define DSREAD(BUF)                                                 \
  {                                                                 \
    const _Float16* kb_ = &kt[BUF][0];                              \
    _Pragma("unroll")                                               \
    for (int ks = 0; ks < 8; ++ks)                                  \
      bf[ks] = *(const half8*)(kb_ + ks * 512 + lane * 8);          \
  }
#define LOADV(T2, VQ)                                               \
  {                                                                 \
    const float* vf_ = vfb + (size_t)(T2) * 4096;                   \
    VQ[0] = *(const f32x4*)(vf_);                                   \
    VQ[1] = *(const f32x4*)(vf_ + 256);                             \
  }
#define MFMA_INTO(ACC)                                              \
  {                                                                 \
    __builtin_amdgcn_s_setprio(1);                                  \
    ACC[0] = __builtin_amdgcn_mfma_f32_16x16x32_f16(                \
        afrag[0][0], bf[0], zeroc, 0, 0, 0);                        \
    ACC[1] = __builtin_amdgcn_mfma_f32_16x16x32_f16(                \
        afrag[1][0], bf[0], zeroc, 0, 0, 0);                        \
    _Pragma("unroll")                                               \
    for (int ks = 1; ks < 8; ++ks) {                                \
      ACC[0] = __builtin_amdgcn_mfma_f32_16x16x32_f16(              \
          afrag[0][ks], bf[ks], ACC[0], 0, 0, 0);                   \
      ACC[1] = __builtin_amdgcn_mfma_f32_16x16x32_f16(              \
          afrag[1][ks], bf[ks], ACC[1], 0, 0, 0);                   \
    }                                                               \
    __builtin_amdgcn_s_setprio(0);                                  \
  }
#define UPDATE(ACC, VQ)                                             \
  {                                                                 \
    _Pragma("unroll")                                               \
    for (int i = 0; i < 2; ++i)                                     \
      _Pragma("unroll")                                             \
      for (int j = 0; j < 4; ++j) {                                 \
        const int s = i * 4 + j;                                    \
        const float L = ACC[i][j];                                  \
        mst[s] = fmaxf(mst[s], L);                                  \
        const float p = L * __builtin_amdgcn_exp2f(L);              \
        sst[s] += fabsf(p);                                         \
        vst[s] = fmaf(VQ[i][j], p, vst[s]);                         \
      }                                                             \
  }

  // ---- prologue ----
  LOADV(0, vqA);
  __syncthreads();            // stage(0) complete
  DSREAD(0);
  stage(1);
  MFMA_INTO(accA);            // tile 0

#pragma unroll 1
  for (int t = 1; t < 31; t += 2) {
    __syncthreads();          // stage(t) complete; buf[(t+1)&1] free
    DSREAD(t & 1);
    LOADV(t, vqB);
    stage(t + 1);
    MFMA_INTO(accB);          // tile t
    UPDATE(accA, vqA);        // tile t-1 (overlaps MFMA pipe)

    __syncthreads();          // stage(t+1) complete
    DSREAD((t + 1) & 1);
    LOADV(t + 1, vqA);
    if (t + 2 < 32) stage(t + 2);
    MFMA_INTO(accA);          // tile t+1
    UPDATE(accB, vqB);        // tile t
  }

  // ---- epilogue: tile 31 ----
  __syncthreads();            // stage(31) complete
  DSREAD(1);
  LOADV(31, vqB);
  MFMA_INTO(accB);            // tile 31
  UPDATE(accA, vqA);          // tile 30
  UPDATE(accB, vqB);          // tile 31

#undef DSREAD
#undef LOADV
#undef MFMA_INTO
#undef UPDATE

#pragma unroll
  for (int mask = 1; mask <= 8; mask <<= 1) {
#pragma unroll
    for (int s = 0; s < 8; ++s) {
      mst[s] = fmaxf(mst[s], __shfl_xor(mst[s], mask));
      sst[s] += __shfl_xor(sst[s], mask);
      vst[s] += __shfl_xor(vst[s], mask);
    }
  }

  if (c == 0) {
    float* orow = vsum + (size_t)(b * SS + sq) * DD;
#pragma unroll
    for (int i = 0; i < 2; ++i) {
      f32x4 o;
#pragma unroll
      for (int j = 0; j < 4; ++j) {
        const int s = i * 4 + j;
        const float tt = LN2 * __builtin_amdgcn_exp2f(-mst[s]);
        o[j] = vst[s] * tt / (sst[s] * tt + 1.0f);
      }
      *(f32x4*)(orow + sbase + i * 16 + g * 4) = o;
    }
  }
}

// ------------------------------------------------------------------
extern "C" void kernel_launch(void* const* d_in, const int* in_sizes, int n_in,
                              void* d_out, int out_size, void* d_ws, size_t ws_size,
                              hipStream_t stream) {
  const float* x     = (const float*)d_in[0];
  const float* w_pre = (const float*)d_in[1];
  const float* w_q   = (const float*)d_in[2];
  const float* w_k   = (const float*)d_in[3];
  const float* w_va  = (const float*)d_in[4];
  const float* w_al  = (const float*)d_in[5];
  const float* w_vo  = (const float*)d_in[6];
  const float* w_end = (const float*)d_in[7];
  float* out = (float*)d_out;

  char* ws = (char*)d_ws;
  float*    X     = (float*)(ws);                          // 1MB
  float*    Y     = (float*)(ws + (1 << 20));              // 1MB
  float*    vsum  = (float*)(ws + (2 << 20));              // 1MB
  _Float16* qf16  = (_Float16*)(ws + (3 << 20));           // 512KB
  _Float16* kfrag = (_Float16*)(ws + (3 << 20) + (512 << 10));  // 512KB
  float*    vfrag = (float*)(ws + (4 << 20));              // 1MB
  unsigned short* wbf = (unsigned short*)(ws + (5 << 20)); // 896KB
  // wbf slots: 0 unused, 1 q, 2 k, 3 va, 4 vo, 5 end, 6 walI(f16)

  prep_and_X<<<448, 256, 0, stream>>>(x, w_pre, w_q, w_k, w_va, w_vo, w_end,
                                      w_al, wbf, X);
  linear_qkv<<<256, 256, 0, stream>>>(X, wbf + 1 * 65536, wbf + 2 * 65536,
                                      wbf + 3 * 65536, qf16, kfrag, vfrag);
  fractal_attn<<<2048, 256, 0, stream>>>((const _Float16*)(wbf + 6 * 65536),
                                         qf16, kfrag, vfrag, vsum);
  linear_bf<<<256, 256, 0, stream>>>(vsum, wbf + 4 * 65536, vsum, X, Y);
  linear_bf<<<256, 256, 0, stream>>>(Y, wbf + 5 * 65536, nullptr, nullptr, out);
}

// Round 18
// 114.578 us; speedup vs baseline: 2.1103x; 2.1103x over previous
//
#include <hip/hip_runtime.h>
#include <hip/hip_bf16.h>

// FractalTransformer fused kernels, round 18.
// r17 post-mortem: f32 v-fragments added +12 VGPR to the attn live set
// (163 -> 175) past the launch_bounds(256,3) budget of 168 -> scratch
// spill (FETCH 148MB), 240us. Headroom at this budget is ~zero.
// r18 = r16's linear_qkv + fractal_attn VERBATIM (f16 v, 98.2us proven)
// + r17's prep_and_X fusion (5 dispatches total).

typedef __attribute__((ext_vector_type(8))) short short8;
typedef __attribute__((ext_vector_type(4))) float f32x4;
typedef __attribute__((ext_vector_type(8))) _Float16 half8;
typedef __attribute__((ext_vector_type(4))) _Float16 half4;

#define DD 256
#define SS 512
#define LOG2E 1.4426950408889634f
#define LN2   0.6931471805599453f

__device__ __forceinline__ unsigned short f2bf(float f) {
  unsigned int b = __float_as_uint(f);
  b += 0x7FFFu + ((b >> 16) & 1u);   // RNE
  return (unsigned short)(b >> 16);
}
__device__ __forceinline__ short8 cvt8(f32x4 lo, f32x4 hi) {
  short8 r;
  r[0]=(short)f2bf(lo[0]); r[1]=(short)f2bf(lo[1]);
  r[2]=(short)f2bf(lo[2]); r[3]=(short)f2bf(lo[3]);
  r[4]=(short)f2bf(hi[0]); r[5]=(short)f2bf(hi[1]);
  r[6]=(short)f2bf(hi[2]); r[7]=(short)f2bf(hi[3]);
  return r;
}
__device__ __forceinline__ void gload16(const void* g, void* l) {
  __builtin_amdgcn_global_load_lds(
      (const __attribute__((address_space(1))) void*)g,
      (__attribute__((address_space(3))) void*)l,
      16, 0, 0);
}

// ------------------------------------------------------------------
// Fused: blocks 0..191 convert the 6 weights still needed (q,k,va,vo,end
// -> bf16; wal+I -> f16); blocks 192..447 compute X = x @ w_pre^T.
// ------------------------------------------------------------------
__global__ __launch_bounds__(256) void prep_and_X(
    const float* __restrict__ x,  const float* __restrict__ w_pre,
    const float* __restrict__ w1, const float* __restrict__ w2,
    const float* __restrict__ w3, const float* __restrict__ w4,
    const float* __restrict__ w5, const float* __restrict__ wal,
    unsigned short* __restrict__ wbf, float* __restrict__ X)
{
  const int bi = blockIdx.x;
  const int tid = threadIdx.x;
  if (bi < 192) {
    const int m = 1 + (bi >> 5);           // wbf slots 1..6
    const int off = ((bi & 31) * 256 + tid) * 8;
    const float* src = m==1?w1: m==2?w2: m==3?w3: m==4?w4: m==5?w5: wal;
    f32x4 a = *(const f32x4*)(src + off);
    f32x4 b = *(const f32x4*)(src + off + 4);
    if (m == 6) {                          // wal: fold +I, store f16
      const int e = off >> 8, d = off & 255;
#pragma unroll
      for (int jj = 0; jj < 4; ++jj) {
        if (e == d + jj)     a[jj] += 1.0f;
        if (e == d + 4 + jj) b[jj] += 1.0f;
      }
      half8 h;
#pragma unroll
      for (int jj = 0; jj < 4; ++jj) {
        h[jj]     = (_Float16)a[jj];
        h[jj + 4] = (_Float16)b[jj];
      }
      *(half8*)(wbf + (size_t)m * 65536 + off) = h;
    } else {
      *(short8*)(wbf + (size_t)m * 65536 + off) = cvt8(a, b);
    }
    return;
  }

  // ---- X = x @ w_pre^T ----
  const int bi2 = bi - 192;
  const int rb = (bi2 >> 2) * 16;
  const int cb = (bi2 & 3) * 64;
  const int wv = tid >> 6, lane = tid & 63;
  const int g = lane >> 4, c = lane & 15;
  const int arow = rb + c;
  const int wrow = cb + wv * 16 + c;

  f32x4 acc = (f32x4){0.f, 0.f, 0.f, 0.f};
#pragma unroll
  for (int ks = 0; ks < 8; ++ks) {
    const int d0 = ks * 32 + g * 8;
    f32x4 a0 = *(const f32x4*)(x + arow * DD + d0);
    f32x4 a1 = *(const f32x4*)(x + arow * DD + d0 + 4);
    short8 av = cvt8(a0, a1);
    f32x4 b0 = *(const f32x4*)(w_pre + wrow * DD + d0);
    f32x4 b1 = *(const f32x4*)(w_pre + wrow * DD + d0 + 4);
    short8 bv = cvt8(b0, b1);
    acc = __builtin_amdgcn_mfma_f32_16x16x32_bf16(av, bv, acc, 0, 0, 0);
  }
#pragma unroll
  for (int j = 0; j < 4; ++j)
    X[(rb + g * 4 + j) * DD + cb + wv * 16 + c] = acc[j];
}

// ------------------------------------------------------------------
// out[1024,256] = A @ Wbf^T (+res1)(+res2). grid 256 = 64 rowblk x 4 colblk.
// ------------------------------------------------------------------
__global__ __launch_bounds__(256) void linear_bf(
    const float* __restrict__ A, const unsigned short* __restrict__ Wbf,
    const float* __restrict__ res1, const float* __restrict__ res2,
    float* __restrict__ out)
{
  const int bi = blockIdx.x;
  const int rb = (bi >> 2) * 16;
  const int cb = (bi & 3) * 64;
  const int tid = threadIdx.x;
  const int wv = tid >> 6, lane = tid & 63;
  const int g = lane >> 4, c = lane & 15;
  const int arow = rb + c;
  const int wrow = cb + wv * 16 + c;

  f32x4 acc = (f32x4){0.f, 0.f, 0.f, 0.f};
#pragma unroll
  for (int ks = 0; ks < 8; ++ks) {
    const int d0 = ks * 32 + g * 8;
    f32x4 a0 = *(const f32x4*)(A + arow * DD + d0);
    f32x4 a1 = *(const f32x4*)(A + arow * DD + d0 + 4);
    short8 av = cvt8(a0, a1);
    short8 bv = *(const short8*)(Wbf + wrow * DD + d0);
    acc = __builtin_amdgcn_mfma_f32_16x16x32_bf16(av, bv, acc, 0, 0, 0);
  }
#pragma unroll
  for (int j = 0; j < 4; ++j) {
    const int ro = rb + g * 4 + j;
    const int co = cb + wv * 16 + c;
    float v = acc[j];
    if (res1) v += res1[ro * DD + co];
    if (res2) v += res2[ro * DD + co];
    out[ro * DD + co] = v;
  }
}

// ------------------------------------------------------------------
// q = f16((X + X@Wq^T)*log2e);  k,v = f16(X + X@{Wk,Wv}^T), written
// DIRECTLY in fragment-packed order via an LDS transpose (r16 verbatim).
// ------------------------------------------------------------------
__global__ __launch_bounds__(256) void linear_qkv(
    const float* __restrict__ X,
    const unsigned short* __restrict__ Wq, const unsigned short* __restrict__ Wk,
    const unsigned short* __restrict__ Wv,
    _Float16* __restrict__ qout,
    _Float16* __restrict__ kfrag, _Float16* __restrict__ vfrag)
{
  __shared__ _Float16 kl[16][64];
  __shared__ _Float16 vl[16][64];

  const int bi = blockIdx.x;
  const int rb = (bi >> 2) * 16;
  const int cb = (bi & 3) * 64;
  const int tid = threadIdx.x;
  const int wv = tid >> 6, lane = tid & 63;
  const int g = lane >> 4, c = lane & 15;
  const int arow = rb + c;
  const int wrow = cb + wv * 16 + c;

  f32x4 aq = (f32x4){0.f,0.f,0.f,0.f};
  f32x4 ak = (f32x4){0.f,0.f,0.f,0.f};
  f32x4 av_ = (f32x4){0.f,0.f,0.f,0.f};
#pragma unroll
  for (int ks = 0; ks < 8; ++ks) {
    const int d0 = ks * 32 + g * 8;
    f32x4 a0 = *(const f32x4*)(X + arow * DD + d0);
    f32x4 a1 = *(const f32x4*)(X + arow * DD + d0 + 4);
    short8 af = cvt8(a0, a1);
    short8 bq = *(const short8*)(Wq + wrow * DD + d0);
    aq = __builtin_amdgcn_mfma_f32_16x16x32_bf16(af, bq, aq, 0, 0, 0);
    short8 bk = *(const short8*)(Wk + wrow * DD + d0);
    ak = __builtin_amdgcn_mfma_f32_16x16x32_bf16(af, bk, ak, 0, 0, 0);
    short8 bv = *(const short8*)(Wv + wrow * DD + d0);
    av_ = __builtin_amdgcn_mfma_f32_16x16x32_bf16(af, bv, av_, 0, 0, 0);
  }
#pragma unroll
  for (int j = 0; j < 4; ++j) {
    const int ro = rb + g * 4 + j;
    const int co = cb + wv * 16 + c;
    const float base = X[ro * DD + co];
    qout[ro * DD + co] = (_Float16)((base + aq[j]) * LOG2E);
    kl[g * 4 + j][wv * 16 + c] = (_Float16)(base + ak[j]);
    vl[g * 4 + j][wv * 16 + c] = (_Float16)(base + av_[j]);
  }
  __syncthreads();

  const int b  = rb >> 9;
  const int t2 = (rb >> 4) & 31;
  const int cg = cb >> 5;                  // ks / slice base (0,2,4,6)

  if (tid < 128) {
    const int ksl = tid >> 6, lane2 = tid & 63;
    const int g2 = lane2 >> 4, c2 = lane2 & 15;
    half8 h = *(const half8*)&kl[c2][ksl * 32 + g2 * 8];
    *(half8*)(kfrag + (size_t)b * 131072 + (size_t)t2 * 4096
              + (cg + ksl) * 512 + lane2 * 8) = h;
  }
  {
    const int sl = tid >> 7, il = (tid >> 6) & 1, lane2 = tid & 63;
    const int g2 = lane2 >> 4, c2 = lane2 & 15;
    half4 h = *(const half4*)&vl[c2][sl * 32 + il * 16 + g2 * 4];
    *(half4*)(vfrag + (size_t)b * 131072 + (size_t)t2 * 4096
              + (cg + sl) * 512 + il * 256 + lane2 * 4) = h;
  }
}

// ------------------------------------------------------------------
// Fused fractal attention — r11/r16 VERBATIM (98.2us proven).
// ------------------------------------------------------------------
__global__ __launch_bounds__(256, 3) void fractal_attn(
    const _Float16* __restrict__ walI,   // f16 (wal+I), [256][256]
    const _Float16* __restrict__ qf,     // f16, pre-scaled by log2e
    const _Float16* __restrict__ kfrag,  // f16 fragment-packed
    const _Float16* __restrict__ vfrag,  // f16 fragment-packed (slice-32)
    float* __restrict__ vsum)
{
  __shared__ _Float16 kt[2][4096];       // 2 x 8KB k tiles

  const int bid = blockIdx.x;            // 2048
  const int eh = bid & 1;
  const int sq = (bid >> 1) & 511;
  const int b  = bid >> 10;
  const int tid = threadIdx.x;
  const int wv = tid >> 6;
  const int lane = tid & 63;
  const int g = lane >> 4, c = lane & 15;
  const int slice = eh * 4 + wv;
  const int sbase = slice * 32;

  const _Float16* ktile0 = kfrag + (size_t)b * 131072;
  auto stage = [&](int t) {
    const _Float16* src = ktile0 + (size_t)t * 4096;
    _Float16* dst = &kt[t & 1][0];
    gload16(src + tid * 8,        dst + tid * 8);
    gload16(src + 2048 + tid * 8, dst + 2048 + tid * 8);
  };

  stage(0);   // completes while we build A'

  half8 afrag[2][8];
  {
    const _Float16* qrow = qf + (size_t)(b * SS + sq) * DD;
    half8 q8[8];
#pragma unroll
    for (int ks = 0; ks < 8; ++ks)
      q8[ks] = *(const half8*)(qrow + ks * 32 + g * 8);
#pragma unroll
    for (int i = 0; i < 2; ++i) {
      const int e = sbase + i * 16 + c;
      const _Float16* wrow = walI + (size_t)e * DD;
#pragma unroll
      for (int ks = 0; ks < 8; ++ks)
        afrag[i][ks] = (*(const half8*)(wrow + ks * 32 + g * 8)) * q8[ks];
    }
  }

  const _Float16* vfb = vfrag + (size_t)b * 131072 + slice * 512 + lane * 4;

  float mst[8], sst[8], vst[8];
#pragma unroll
  for (int s = 0; s < 8; ++s) { mst[s] = -1e30f; sst[s] = 0.f; vst[s] = 0.f; }

  half8 bf[8];
  half4 vqA[2], vqB[2];
  f32x4 accA[2], accB[2];
  const f32x4 zeroc = (f32x4){0.f, 0.f, 0.f, 0.f};

#define DSREAD(BUF)                                                 \
  {                                                                 \
    const _Float16* kb_ = &kt[BUF][0];                              \
    _Pragma("unroll")                                               \
    for (int ks = 0; ks < 8; ++ks)                                  \
      bf[ks] = *(const half8*)(kb_ + ks * 512 + lane * 8);          \
  }
#define LOADV(T2, VQ)                                               \
  {                                                                 \
    const _Float16* vf_ = vfb + (size_t)(T2) * 4096;                \
    VQ[0] = *(const half4*)(vf_);                                   \
    VQ[1] = *(const half4*)(vf_ + 256);                             \
  }
#define MFMA_INTO(ACC)                                              \
  {                                                                 \
    __builtin_amdgcn_s_setprio(1);                                  \
    ACC[0] = __builtin_amdgcn_mfma_f32_16x16x32_f16(                \
        afrag[0][0], bf[0], zeroc, 0, 0, 0);                        \
    ACC[1] = __builtin_amdgcn_mfma_f32_16x16x32_f16(                \
        afrag[1][0], bf[0], zeroc, 0, 0, 0);                        \
    _Pragma("unroll")                                               \
    for (int ks = 1; ks < 8; ++ks) {                                \
      ACC[0] = __builtin_amdgcn_mfma_f32_16x16x32_f16(              \
          afrag[0][ks], bf[ks], ACC[0], 0, 0, 0);                   \
      ACC[1] = __builtin_amdgcn_mfma_f32_16x16x32_f16(              \
          afrag[1][ks], bf[ks], ACC[1], 0, 0, 0);                   \
    }                                                               \
    __builtin_amdgcn_s_setprio(0);                                  \
  }
#define UPDATE(ACC, VQ)                                             \
  {                                                                 \
    _Pragma("unroll")                                               \
    for (int i = 0; i < 2; ++i)                                     \
      _Pragma("unroll")                                             \
      for (int j = 0; j < 4; ++j) {                                 \
        const int s = i * 4 + j;                                    \
        const float L = ACC[i][j];                                  \
        mst[s] = fmaxf(mst[s], L);                                  \
        const float p = L * __builtin_amdgcn_exp2f(L);              \
        sst[s] += fabsf(p);                                         \
        vst[s] = fmaf((float)VQ[i][j], p, vst[s]);                  \
      }                                                             \
  }

  // ---- prologue ----
  LOADV(0, vqA);
  __syncthreads();            // stage(0) complete
  DSREAD(0);
  stage(1);
  MFMA_INTO(accA);            // tile 0

#pragma unroll 1
  for (int t = 1; t < 31; t += 2) {
    __syncthreads();          // stage(t) complete; buf[(t+1)&1] free
    DSREAD(t & 1);
    LOADV(t, vqB);
    stage(t + 1);
    MFMA_INTO(accB);          // tile t
    UPDATE(accA, vqA);        // tile t-1 (overlaps MFMA pipe)

    __syncthreads();          // stage(t+1) complete
    DSREAD((t + 1) & 1);
    LOADV(t + 1, vqA);
    if (t + 2 < 32) stage(t + 2);
    MFMA_INTO(accA);          // tile t+1
    UPDATE(accB, vqB);        // tile t
  }

  // ---- epilogue: tile 31 ----
  __syncthreads();            // stage(31) complete
  DSREAD(1);
  LOADV(31, vqB);
  MFMA_INTO(accB);            // tile 31
  UPDATE(accA, vqA);          // tile 30
  UPDATE(accB, vqB);          // tile 31

#undef DSREAD
#undef LOADV
#undef MFMA_INTO
#undef UPDATE

#pragma unroll
  for (int mask = 1; mask <= 8; mask <<= 1) {
#pragma unroll
    for (int s = 0; s < 8; ++s) {
      mst[s] = fmaxf(mst[s], __shfl_xor(mst[s], mask));
      sst[s] += __shfl_xor(sst[s], mask);
      vst[s] += __shfl_xor(vst[s], mask);
    }
  }

  if (c == 0) {
    float* orow = vsum + (size_t)(b * SS + sq) * DD;
#pragma unroll
    for (int i = 0; i < 2; ++i) {
      f32x4 o;
#pragma unroll
      for (int j = 0; j < 4; ++j) {
        const int s = i * 4 + j;
        const float tt = LN2 * __builtin_amdgcn_exp2f(-mst[s]);
        o[j] = vst[s] * tt / (sst[s] * tt + 1.0f);
      }
      *(f32x4*)(orow + sbase + i * 16 + g * 4) = o;
    }
  }
}

// ------------------------------------------------------------------
extern "C" void kernel_launch(void* const* d_in, const int* in_sizes, int n_in,
                              void* d_out, int out_size, void* d_ws, size_t ws_size,
                              hipStream_t stream) {
  const float* x     = (const float*)d_in[0];
  const float* w_pre = (const float*)d_in[1];
  const float* w_q   = (const float*)d_in[2];
  const float* w_k   = (const float*)d_in[3];
  const float* w_va  = (const float*)d_in[4];
  const float* w_al  = (const float*)d_in[5];
  const float* w_vo  = (const float*)d_in[6];
  const float* w_end = (const float*)d_in[7];
  float* out = (float*)d_out;

  char* ws = (char*)d_ws;
  float*    X     = (float*)(ws);                          // 1MB
  float*    Y     = (float*)(ws + (1 << 20));              // 1MB
  float*    vsum  = (float*)(ws + (2 << 20));              // 1MB
  _Float16* qf16  = (_Float16*)(ws + (3 << 20));           // 512KB
  _Float16* kfrag = (_Float16*)(ws + (3 << 20) + (512 << 10));  // 512KB
  _Float16* vfrag = (_Float16*)(ws + (4 << 20));           // 512KB
  unsigned short* wbf = (unsigned short*)(ws + (4 << 20) + (512 << 10));
  // wbf slots: 0 unused, 1 q, 2 k, 3 va, 4 vo, 5 end, 6 walI(f16)

  prep_and_X<<<448, 256, 0, stream>>>(x, w_pre, w_q, w_k, w_va, w_vo, w_end,
                                      w_al, wbf, X);
  linear_qkv<<<256, 256, 0, stream>>>(X, wbf + 1 * 65536, wbf + 2 * 65536,
                                      wbf + 3 * 65536, qf16, kfrag, vfrag);
  fractal_attn<<<2048, 256, 0, stream>>>((const _Float16*)(wbf + 6 * 65536),
                                         qf16, kfrag, vfrag, vsum);
  linear_bf<<<256, 256, 0, stream>>>(vsum, wbf + 4 * 65536, vsum, X, Y);
  linear_bf<<<256, 256, 0, stream>>>(Y, wbf + 5 * 65536, nullptr, nullptr, out);
}